// Round 3
// baseline (1206.199 us; speedup 1.0000x reference)
//
#include <hip/hip_runtime.h>

#define HID 50
#define NMID 7
#define BLOCK 256
// LDS row stride 51 floats: bank step 51%32=19, gcd(19,32)=1 -> a wave's 64
// lanes spread over all 32 banks = 2-way aliasing = free (m136).
#define HSTRIDE 51

__device__ __forceinline__ float tanh_fast(float v) {
    // tanh(x) = 1 - 2/(exp(2x)+1); exp(2x) = exp2(x * 2*log2(e))
    float e = __builtin_amdgcn_exp2f(v * 2.885390081777927f);
    return 1.0f - 2.0f * __builtin_amdgcn_rcpf(e + 1.0f);
}

// h[] lives in LDS (per-thread private row), acc[] in VGPRs. This keeps the
// per-thread register live set ~65 floats so the allocator never falls into
// the AGPR-storage mode that cost rounds 1-2 a 2.5x VALU-issue overhead
// (52 VGPR + ~88 AGPR, v_accvgpr_read per FMA, 38% useful-FMA fraction).
__global__ __launch_bounds__(BLOCK) void softmesh_mlp(
    const float* __restrict__ x, const float* __restrict__ y,
    const float* __restrict__ z,
    const float* __restrict__ W_in, const float* __restrict__ b_in,
    const float* __restrict__ W_mid, const float* __restrict__ b_mid,
    const float* __restrict__ W_out, const float* __restrict__ b_out,
    float* __restrict__ out, int n)
{
    __shared__ float hsm[BLOCK * HSTRIDE];
    const int tid = threadIdx.x;
    float* __restrict__ hrow = &hsm[tid * HSTRIDE];

    const int i = blockIdx.x * BLOCK + tid;
    if (i >= n) return;   // no __syncthreads anywhere: each thread touches only its own LDS row

    const float in0 = x[i];
    const float in1 = y[i];
    const float in2 = z[i];

    // ---- input layer: [3] @ [3,50] + b -> tanh -> LDS ----
#pragma unroll
    for (int j = 0; j < HID; ++j) {
        float a = b_in[j];
        a = fmaf(in0, W_in[0 * HID + j], a);
        a = fmaf(in1, W_in[1 * HID + j], a);
        a = fmaf(in2, W_in[2 * HID + j], a);
        hrow[j] = tanh_fast(a);
    }

    float acc[HID];

    // ---- mid layers 0..5: h_new = tanh(h @ W + b), h via LDS ----
#pragma unroll 1   // keep layer loop rolled: body ~2500 v_fmac, x7 blows I-cache
    for (int L = 0; L < NMID - 1; ++L) {
        const float* __restrict__ W = W_mid + L * HID * HID;
        const float* __restrict__ b = b_mid + L * HID;
#pragma unroll
        for (int j = 0; j < HID; ++j) acc[j] = b[j];
#pragma unroll
        for (int k = 0; k < HID; ++k) {
            const float hk = hrow[k];          // 1 ds_read_b32, reused 50x
#pragma unroll
            for (int j = 0; j < HID; ++j) {
                // W row k contiguous + wave-uniform -> s_load; fmac src0=SGPR
                acc[j] = fmaf(hk, W[k * HID + j], acc[j]);
            }
        }
#pragma unroll
        for (int j = 0; j < HID; ++j) hrow[j] = tanh_fast(acc[j]);
    }

    // ---- last mid layer fused with output layer (no LDS round-trip) ----
    {
        const float* __restrict__ W = W_mid + (NMID - 1) * HID * HID;
        const float* __restrict__ b = b_mid + (NMID - 1) * HID;
#pragma unroll
        for (int j = 0; j < HID; ++j) acc[j] = b[j];
#pragma unroll
        for (int k = 0; k < HID; ++k) {
            const float hk = hrow[k];
#pragma unroll
            for (int j = 0; j < HID; ++j) {
                acc[j] = fmaf(hk, W[k * HID + j], acc[j]);
            }
        }
    }

    float u0 = b_out[0];
    float u1 = b_out[1];
    float u2 = b_out[2];
#pragma unroll
    for (int k = 0; k < HID; ++k) {
        const float hk = tanh_fast(acc[k]);
        u0 = fmaf(hk, W_out[k * 3 + 0], u0);
        u1 = fmaf(hk, W_out[k * 3 + 1], u1);
        u2 = fmaf(hk, W_out[k * 3 + 2], u2);
    }

    // outputs: tuple (U[:,0], U[:,1], U[:,2]) concatenated flat
    out[i]         = u0;
    out[i + n]     = u1;
    out[i + 2 * n] = u2;
}

extern "C" void kernel_launch(void* const* d_in, const int* in_sizes, int n_in,
                              void* d_out, int out_size, void* d_ws, size_t ws_size,
                              hipStream_t stream) {
    const float* x     = (const float*)d_in[0];
    const float* y     = (const float*)d_in[1];
    const float* z     = (const float*)d_in[2];
    const float* W_in  = (const float*)d_in[3];
    const float* b_in  = (const float*)d_in[4];
    const float* W_mid = (const float*)d_in[5];
    const float* b_mid = (const float*)d_in[6];
    const float* W_out = (const float*)d_in[7];
    const float* b_out = (const float*)d_in[8];
    float* out = (float*)d_out;

    int n = in_sizes[0];
    int grid = (n + BLOCK - 1) / BLOCK;
    softmesh_mlp<<<grid, BLOCK, 0, stream>>>(x, y, z, W_in, b_in, W_mid, b_mid,
                                             W_out, b_out, out, n);
}

// Round 5
// 732.337 us; speedup vs baseline: 1.6471x; 1.6471x over previous
//
#include <hip/hip_runtime.h>

#define HID 50
#define NMID 7

// ---- packed-parameter workspace layout (ushort units for weights) ----
// WpackMid [L][t][s][64 lanes][8] : 7*4*5*64*8 = 71680 ushorts
// WpackIn  [t][64][8]             : 2048
// WpackOut [s][64][8]             : 2560
// biases (float, after 76288 ushorts = 152576 B): b_in[64], b_mid[7][64], b_out[64]
#define MID_ELEMS (NMID * 4 * 5 * 64 * 8)
#define IN_ELEMS  (4 * 64 * 8)
#define OUT_ELEMS (5 * 64 * 8)
#define W_USHORTS (MID_ELEMS + IN_ELEMS + OUT_ELEMS)
#define BIAS_FLOATS (64 + NMID * 64 + 64)
#define PACK_THREADS (W_USHORTS + BIAS_FLOATS)

using short8 = __attribute__((ext_vector_type(8))) short;  // 8 bf16 (4 VGPRs)
using f32x4  = __attribute__((ext_vector_type(4))) float;  // MFMA C/D

__device__ __forceinline__ unsigned short bf16_rne(float f) {
    unsigned int u = __builtin_bit_cast(unsigned int, f);
    unsigned int r = (u + 0x7FFFu + ((u >> 16) & 1u)) >> 16;
    return (unsigned short)r;
}
__device__ __forceinline__ float bf16_f(unsigned short b) {
    unsigned int u = ((unsigned int)b) << 16;
    return __builtin_bit_cast(float, u);
}
__device__ __forceinline__ unsigned short bf16_lo(float w) {
    return bf16_rne(w - bf16_f(bf16_rne(w)));
}
__device__ __forceinline__ float tanh_fast(float v) {
    // tanh(x) = 1 - 2/(exp(2x)+1)
    float e = __builtin_amdgcn_exp2f(v * 2.885390081777927f);
    return 1.0f - 2.0f * __builtin_amdgcn_rcpf(e + 1.0f);
}

// Prologue: split fp32 params into bf16 hi/lo and lay them out in EXACT
// B-fragment order for mfma_f32_16x16x32_bf16: B[n = lane&15][k = (lane>>4)*8+j].
// Logical W' per mid layer (K'=160 x N=64): rows 0..49 = W_hi, 50..99 = W_lo,
// 100..149 = W_hi, 150..159 = 0; cols >=50 = 0.  (pairs with h = [hi|hi|lo|0])
__global__ void pack_params(const float* __restrict__ W_in, const float* __restrict__ b_in,
                            const float* __restrict__ W_mid, const float* __restrict__ b_mid,
                            const float* __restrict__ W_out, const float* __restrict__ b_out,
                            unsigned short* __restrict__ wp, float* __restrict__ bp) {
    int e = blockIdx.x * 256 + threadIdx.x;
    if (e < MID_ELEMS) {
        int L = e / 10240, r1 = e % 10240;
        int t = r1 / 2560,  r2 = r1 % 2560;
        int s = r2 / 512,   r3 = r2 % 512;
        int l = r3 / 8,     j  = r3 % 8;
        int k  = s * 32 + (l >> 4) * 8 + j;
        int nn = t * 16 + (l & 15);
        unsigned short bits = 0;
        if (nn < HID) {
            const float* W = W_mid + L * HID * HID;
            if (k < 50)       bits = bf16_rne(W[k * HID + nn]);
            else if (k < 100) bits = bf16_lo (W[(k - 50) * HID + nn]);
            else if (k < 150) bits = bf16_rne(W[(k - 100) * HID + nn]);
        }
        wp[e] = bits;
    } else if (e < MID_ELEMS + IN_ELEMS) {
        int e2 = e - MID_ELEMS;
        int t = e2 / 512, r = e2 % 512, l = r / 8, j = r % 8;
        int k  = (l >> 4) * 8 + j;          // single k-step
        int nn = t * 16 + (l & 15);
        unsigned short bits = 0;
        if (nn < HID) {
            // A slots: [xh,yh,zh, xl,yl,zl, xh,yh | zh ...] pair with
            // W'_in rows: [Whi(3) | Whi(3) | Wlo(3) | 0...]
            if (k < 3)      bits = bf16_rne(W_in[k * HID + nn]);
            else if (k < 6) bits = bf16_rne(W_in[(k - 3) * HID + nn]);
            else if (k < 9) bits = bf16_lo (W_in[(k - 6) * HID + nn]);
        }
        wp[e] = bits;
    } else if (e < W_USHORTS) {
        int e3 = e - MID_ELEMS - IN_ELEMS;
        int s = e3 / 512, r = e3 % 512, l = r / 8, j = r % 8;
        int k  = s * 32 + (l >> 4) * 8 + j;
        int nn = l & 15;
        unsigned short bits = 0;
        if (nn < 3) {
            if (k < 50)       bits = bf16_rne(W_out[k * 3 + nn]);
            else if (k < 100) bits = bf16_lo (W_out[(k - 50) * 3 + nn]);
            else if (k < 150) bits = bf16_rne(W_out[(k - 100) * 3 + nn]);
        }
        wp[e] = bits;
    } else if (e < PACK_THREADS) {
        int b = e - W_USHORTS;
        float v = 0.0f;
        if (b < 64)                 { if (b < HID) v = b_in[b]; }
        else if (b < 64 + NMID*64)  { int L = (b - 64) / 64, c = (b - 64) % 64;
                                      if (c < HID) v = b_mid[L * HID + c]; }
        else                        { int c = b - 64 - NMID * 64;
                                      if (c < 3) v = b_out[c]; }
        bp[b] = v;
    }
}

// LDS row: 160 bf16 = [h_hi(50) | h_hi(50) | h_lo(50) | pad(10)], stride 168
// ushorts (336 B, 16B-aligned). Per-wave-private region: no __syncthreads.
// CRITICAL (round-4 NaN): positions 150..159 are READ by the A-fragment loads
// (k=150..159) but never written by the epilogue. LDS starts undefined ->
// NaN x 0 = NaN through the MFMA. Zero them once at wave start.
#define LROW 168

__global__ __launch_bounds__(256) void softmesh_mfma(
    const float* __restrict__ x, const float* __restrict__ y,
    const float* __restrict__ z,
    const unsigned short* __restrict__ wp, const float* __restrict__ bp,
    float* __restrict__ out, int n)
{
    __shared__ unsigned short hsm[4 * 16 * LROW];
    const int tid  = threadIdx.x;
    const int wave = tid >> 6, lane = tid & 63;
    const int m = lane & 15, quad = lane >> 4;
    unsigned short* __restrict__ hb = hsm + wave * 16 * LROW;

    const int i0 = (blockIdx.x * 4 + wave) * 16;
    if (i0 >= n) return;
    int idx = i0 + m; if (idx >= n) idx = n - 1;

    // zero k-pad 150..159 in all 16 rows (80 dwords, lanes cooperate)
#pragma unroll
    for (int t = lane; t < 80; t += 64) {
        int row = t / 5, d = t % 5;
        *(unsigned int*)(hb + row * LROW + 150 + d * 2) = 0u;
    }

    const short8* __restrict__ Wm = (const short8*)wp;                          // [L][t][s][64]
    const short8* __restrict__ Wi = (const short8*)(wp + MID_ELEMS);            // [t][64]
    const short8* __restrict__ Wo = (const short8*)(wp + MID_ELEMS + IN_ELEMS); // [s][64]
    const float* __restrict__ bin  = bp;
    const float* __restrict__ bmid = bp + 64;
    const float* __restrict__ bout = bp + 64 + NMID * 64;

    // ---- input layer: A-fragment built in registers (K=32, 1 k-step) ----
    float xv = x[idx], yv = y[idx], zv = z[idx];
    unsigned short xh = bf16_rne(xv), yh = bf16_rne(yv), zh = bf16_rne(zv);
    unsigned short xl = bf16_lo(xv),  yl = bf16_lo(yv),  zl = bf16_lo(zv);
    short8 af = (short8){0, 0, 0, 0, 0, 0, 0, 0};
    if (quad == 0) {
        af[0] = (short)xh; af[1] = (short)yh; af[2] = (short)zh;
        af[3] = (short)xl; af[4] = (short)yl; af[5] = (short)zl;
        af[6] = (short)xh; af[7] = (short)yh;
    } else if (quad == 1) {
        af[0] = (short)zh;
    }

    f32x4 acc[4];
#pragma unroll
    for (int t = 0; t < 4; ++t) {
        float bv = bin[t * 16 + m];
        f32x4 c4 = (f32x4){bv, bv, bv, bv};
        acc[t] = __builtin_amdgcn_mfma_f32_16x16x32_bf16(af, Wi[t * 64 + lane], c4, 0, 0, 0);
    }

    // epilogue: tanh + hi/lo split -> LDS (C-layout: col=t*16+m, row=quad*4+r)
#pragma unroll
    for (int t = 0; t < 4; ++t) {
#pragma unroll
        for (int r = 0; r < 4; ++r) {
            float v = tanh_fast(acc[t][r]);
            unsigned short hi = bf16_rne(v);
            unsigned short lo = bf16_rne(v - bf16_f(hi));
            unsigned short* row = hb + (quad * 4 + r) * LROW;
            int c = t * 16 + m;
            if (t < 3)      { row[c] = hi; row[c + 50] = hi; row[c + 100] = lo; }
            else if (m < 2) { row[c] = hi; row[c + 50] = hi; row[c + 100] = lo; }
        }
    }

    // ---- 7 mid layers: C[16x64] = A[16x160] * W'[160x64] ----
#pragma unroll 1
    for (int L = 0; L < NMID; ++L) {
        short8 a[5];
#pragma unroll
        for (int s = 0; s < 5; ++s)   // A[m=lane&15][k=quad*8+j], k-chunk contiguous
            a[s] = *(const short8*)(hb + m * LROW + s * 32 + quad * 8);
        const short8* __restrict__ WL = Wm + L * 20 * 64;
#pragma unroll
        for (int t = 0; t < 4; ++t) {
            float bv = bmid[L * 64 + t * 16 + m];
            f32x4 c4 = (f32x4){bv, bv, bv, bv};
#pragma unroll
            for (int s = 0; s < 5; ++s)
                c4 = __builtin_amdgcn_mfma_f32_16x16x32_bf16(a[s], WL[(t * 5 + s) * 64 + lane], c4, 0, 0, 0);
            acc[t] = c4;
        }
#pragma unroll
        for (int t = 0; t < 4; ++t) {
#pragma unroll
            for (int r = 0; r < 4; ++r) {
                float v = tanh_fast(acc[t][r]);
                unsigned short hi = bf16_rne(v);
                unsigned short lo = bf16_rne(v - bf16_f(hi));
                unsigned short* row = hb + (quad * 4 + r) * LROW;
                int c = t * 16 + m;
                if (t < 3)      { row[c] = hi; row[c + 50] = hi; row[c + 100] = lo; }
                else if (m < 2) { row[c] = hi; row[c + 50] = hi; row[c + 100] = lo; }
            }
        }
    }

    // ---- output layer: cols 0..2 only (1 N-tile) ----
    {
        short8 a[5];
#pragma unroll
        for (int s = 0; s < 5; ++s)
            a[s] = *(const short8*)(hb + m * LROW + s * 32 + quad * 8);
        float bv = bout[m];
        f32x4 c4 = (f32x4){bv, bv, bv, bv};
#pragma unroll
        for (int s = 0; s < 5; ++s)
            c4 = __builtin_amdgcn_mfma_f32_16x16x32_bf16(a[s], Wo[s * 64 + lane], c4, 0, 0, 0);
        if (m < 3) {
#pragma unroll
            for (int r = 0; r < 4; ++r) {
                int row = i0 + quad * 4 + r;
                if (row < n) out[(size_t)m * (size_t)n + row] = c4[r];
            }
        }
    }
}

extern "C" void kernel_launch(void* const* d_in, const int* in_sizes, int n_in,
                              void* d_out, int out_size, void* d_ws, size_t ws_size,
                              hipStream_t stream) {
    const float* x     = (const float*)d_in[0];
    const float* y     = (const float*)d_in[1];
    const float* z     = (const float*)d_in[2];
    const float* W_in  = (const float*)d_in[3];
    const float* b_in  = (const float*)d_in[4];
    const float* W_mid = (const float*)d_in[5];
    const float* b_mid = (const float*)d_in[6];
    const float* W_out = (const float*)d_in[7];
    const float* b_out = (const float*)d_in[8];
    float* out = (float*)d_out;
    int n = in_sizes[0];

    unsigned short* wp = (unsigned short*)d_ws;
    float* bpf = (float*)((char*)d_ws + W_USHORTS * sizeof(unsigned short));

    int pgrid = (PACK_THREADS + 255) / 256;
    pack_params<<<pgrid, 256, 0, stream>>>(W_in, b_in, W_mid, b_mid, W_out, b_out, wp, bpf);

    int grid = (n + 63) / 64;   // 4 waves/block, 16 points/wave
    softmesh_mfma<<<grid, 256, 0, stream>>>(x, y, z, wp, bpf, out, n);
}